// Round 1
// baseline (405.379 us; speedup 1.0000x reference)
//
#include <hip/hip_runtime.h>

// Problem constants (match reference)
constexpr int N_NODES = 4096;
constexpr int N_EDGES = 4096;
constexpr int F = 128;

// Tiling
constexpr int ETILE  = 64;   // output-tile rows for edge aggregate
constexpr int NTILE  = 64;   // output-tile rows for node aggregate
constexpr int KCHUNK = 32;   // K-dim staged per iteration
constexpr int KSPLIT = 8;    // K-split factor (atomics combine partials)

// ---------------------------------------------------------------------------
// Kernel A: reciprocal of the diagonals of D_v / D_e
// ---------------------------------------------------------------------------
__global__ void k_recip_diag(const float* __restrict__ Dv,
                             const float* __restrict__ De,
                             float* __restrict__ dv_inv,
                             float* __restrict__ de_inv) {
    int i = blockIdx.x * blockDim.x + threadIdx.x;
    if (i < N_NODES) dv_inv[i] = 1.0f / Dv[(size_t)i * (N_NODES + 1)];
    if (i < N_EDGES) de_inv[i] = 1.0f / De[(size_t)i * (N_EDGES + 1)];
}

// ---------------------------------------------------------------------------
// Kernel B: theta = X @ W   [N,128] = [N,128]@[128,128]
// One block = 8 rows, 128 threads (thread = output column).
// ---------------------------------------------------------------------------
__global__ void k_theta(const float* __restrict__ X,
                        const float* __restrict__ W,
                        float* __restrict__ theta) {
    __shared__ float Xs[8][F];
    const int r0 = blockIdx.x * 8;
    const int t  = threadIdx.x;  // 0..127
    #pragma unroll
    for (int i = 0; i < 8; ++i)
        Xs[i][t] = X[(size_t)(r0 + i) * F + t];
    __syncthreads();
    float acc[8];
    #pragma unroll
    for (int i = 0; i < 8; ++i) acc[i] = 0.0f;
    for (int k = 0; k < F; ++k) {
        const float w = W[k * F + t];
        #pragma unroll
        for (int i = 0; i < 8; ++i) acc[i] += Xs[i][k] * w;
    }
    #pragma unroll
    for (int i = 0; i < 8; ++i)
        theta[(size_t)(r0 + i) * F + t] = acc[i];
}

// ---------------------------------------------------------------------------
// Kernel C: M += H^T @ theta   (K = node dim, split KSPLIT ways, atomic merge)
// M[e,f] = sum_n H[n,e] * theta[n,f]
// Block: 256 threads, tile 64 e x 128 f, thread owns 8e x 4f.
// ---------------------------------------------------------------------------
__global__ void k_edge_agg(const float* __restrict__ H,
                           const float* __restrict__ theta,
                           float* __restrict__ M) {
    __shared__ float Hs[KCHUNK][ETILE];   // [n][e] 8 KB
    __shared__ float Ts[KCHUNK][F];       // [n][f] 16 KB
    const int e0 = blockIdx.x * ETILE;
    const int n0 = blockIdx.y * (N_NODES / KSPLIT);
    const int t  = threadIdx.x;           // 0..255
    const int f4 = (t & 31) * 4;
    const int eb = (t >> 5) * 8;

    float4 acc[8];
    #pragma unroll
    for (int i = 0; i < 8; ++i) acc[i] = make_float4(0.f, 0.f, 0.f, 0.f);

    for (int nc = 0; nc < N_NODES / KSPLIT; nc += KCHUNK) {
        // stage H tile: 32x64 floats = 512 float4, 2 per thread (coalesced)
        #pragma unroll
        for (int i = 0; i < 2; ++i) {
            const int idx = t + 256 * i;          // float4 index
            const int nn = idx >> 4, ee4 = (idx & 15) * 4;
            *(float4*)&Hs[nn][ee4] =
                *(const float4*)&H[(size_t)(n0 + nc + nn) * N_EDGES + e0 + ee4];
        }
        // stage theta tile: 32x128 floats = 1024 float4, 4 per thread
        #pragma unroll
        for (int i = 0; i < 4; ++i) {
            const int idx = t + 256 * i;
            const int nn = idx >> 5, ff4 = (idx & 31) * 4;
            *(float4*)&Ts[nn][ff4] =
                *(const float4*)&theta[(size_t)(n0 + nc + nn) * F + ff4];
        }
        __syncthreads();
        #pragma unroll 8
        for (int nn = 0; nn < KCHUNK; ++nn) {
            const float4 th = *(const float4*)&Ts[nn][f4];
            const float4 h0 = *(const float4*)&Hs[nn][eb];
            const float4 h1 = *(const float4*)&Hs[nn][eb + 4];
            const float hv[8] = {h0.x, h0.y, h0.z, h0.w, h1.x, h1.y, h1.z, h1.w};
            #pragma unroll
            for (int i = 0; i < 8; ++i) {
                acc[i].x += hv[i] * th.x;
                acc[i].y += hv[i] * th.y;
                acc[i].z += hv[i] * th.z;
                acc[i].w += hv[i] * th.w;
            }
        }
        __syncthreads();
    }
    #pragma unroll
    for (int i = 0; i < 8; ++i) {
        float* p = &M[(size_t)(e0 + eb + i) * F + f4];
        atomicAdd(p + 0, acc[i].x);
        atomicAdd(p + 1, acc[i].y);
        atomicAdd(p + 2, acc[i].z);
        atomicAdd(p + 3, acc[i].w);
    }
}

// ---------------------------------------------------------------------------
// Kernel D: out += (dv_inv .* H) @ (de_inv .* M)   (K = edge dim, split)
// out[n,f] = dv_inv[n] * sum_e H[n,e] * de_inv[e] * M[e,f]
// Block: 256 threads, tile 64 n x 128 f, thread owns 8n x 4f.
// H staged transposed into LDS (Hs[e][n], pad 68 -> 4-way max on writes).
// ---------------------------------------------------------------------------
__global__ void k_node_agg(const float* __restrict__ H,
                           const float* __restrict__ M,
                           const float* __restrict__ dv_inv,
                           const float* __restrict__ de_inv,
                           float* __restrict__ out) {
    __shared__ float Ms[KCHUNK][F];         // [e][f] scaled by de_inv, 16 KB
    __shared__ float Hs[KCHUNK][68];        // [e][n] scaled by dv_inv, padded
    const int n0 = blockIdx.x * NTILE;
    const int e0 = blockIdx.y * (N_EDGES / KSPLIT);
    const int t  = threadIdx.x;
    const int f4 = (t & 31) * 4;
    const int nb = (t >> 5) * 8;

    float4 acc[8];
    #pragma unroll
    for (int i = 0; i < 8; ++i) acc[i] = make_float4(0.f, 0.f, 0.f, 0.f);

    for (int ec = 0; ec < N_EDGES / KSPLIT; ec += KCHUNK) {
        // stage M tile scaled: 32x128 = 1024 float4, 4 per thread
        #pragma unroll
        for (int i = 0; i < 4; ++i) {
            const int idx = t + 256 * i;
            const int ee = idx >> 5, ff4 = (idx & 31) * 4;
            float4 m = *(const float4*)&M[(size_t)(e0 + ec + ee) * F + ff4];
            const float s = de_inv[e0 + ec + ee];
            m.x *= s; m.y *= s; m.z *= s; m.w *= s;
            *(float4*)&Ms[ee][ff4] = m;
        }
        // stage H tile transposed + scaled: 64n x 32e = 512 float4 reads
        #pragma unroll
        for (int i = 0; i < 2; ++i) {
            const int idx = t + 256 * i;
            const int nn = idx >> 3, ee4 = (idx & 7) * 4;
            const float4 h =
                *(const float4*)&H[(size_t)(n0 + nn) * N_EDGES + e0 + ec + ee4];
            const float s = dv_inv[n0 + nn];
            Hs[ee4 + 0][nn] = h.x * s;
            Hs[ee4 + 1][nn] = h.y * s;
            Hs[ee4 + 2][nn] = h.z * s;
            Hs[ee4 + 3][nn] = h.w * s;
        }
        __syncthreads();
        #pragma unroll 8
        for (int e = 0; e < KCHUNK; ++e) {
            const float4 mv = *(const float4*)&Ms[e][f4];
            const float4 h0 = *(const float4*)&Hs[e][nb];
            const float4 h1 = *(const float4*)&Hs[e][nb + 4];
            const float hv[8] = {h0.x, h0.y, h0.z, h0.w, h1.x, h1.y, h1.z, h1.w};
            #pragma unroll
            for (int i = 0; i < 8; ++i) {
                acc[i].x += hv[i] * mv.x;
                acc[i].y += hv[i] * mv.y;
                acc[i].z += hv[i] * mv.z;
                acc[i].w += hv[i] * mv.w;
            }
        }
        __syncthreads();
    }
    #pragma unroll
    for (int i = 0; i < 8; ++i) {
        float* p = &out[(size_t)(n0 + nb + i) * F + f4];
        atomicAdd(p + 0, acc[i].x);
        atomicAdd(p + 1, acc[i].y);
        atomicAdd(p + 2, acc[i].z);
        atomicAdd(p + 3, acc[i].w);
    }
}

// ---------------------------------------------------------------------------
extern "C" void kernel_launch(void* const* d_in, const int* in_sizes, int n_in,
                              void* d_out, int out_size, void* d_ws, size_t ws_size,
                              hipStream_t stream) {
    const float* X  = (const float*)d_in[0];   // [N,128]
    const float* H  = (const float*)d_in[1];   // [N,E]
    const float* Dv = (const float*)d_in[2];   // [N,N]
    const float* De = (const float*)d_in[3];   // [E,E]
    const float* W  = (const float*)d_in[4];   // [128,128]
    float* out = (float*)d_out;                // [N,128]

    char* ws = (char*)d_ws;
    float* theta  = (float*)ws;                                  // 2 MB
    float* M      = (float*)(ws + (size_t)2 * 1024 * 1024);      // 2 MB
    float* dv_inv = (float*)(ws + (size_t)4 * 1024 * 1024);      // 16 KB
    float* de_inv = dv_inv + N_NODES;                            // 16 KB

    // zero accumulation targets (ws/out are poisoned 0xAA before each call)
    hipMemsetAsync(M,   0, (size_t)N_EDGES * F * sizeof(float), stream);
    hipMemsetAsync(out, 0, (size_t)N_NODES * F * sizeof(float), stream);

    k_recip_diag<<<dim3(N_NODES / 256), dim3(256), 0, stream>>>(Dv, De, dv_inv, de_inv);
    k_theta<<<dim3(N_NODES / 8), dim3(128), 0, stream>>>(X, W, theta);
    k_edge_agg<<<dim3(N_EDGES / ETILE, KSPLIT), dim3(256), 0, stream>>>(H, theta, M);
    k_node_agg<<<dim3(N_NODES / NTILE, KSPLIT), dim3(256), 0, stream>>>(H, M, dv_inv, de_inv, out);
}

// Round 2
// 259.725 us; speedup vs baseline: 1.5608x; 1.5608x over previous
//
#include <hip/hip_runtime.h>

// Problem constants (match reference)
constexpr int N_NODES = 4096;
constexpr int N_EDGES = 4096;
constexpr int F = 128;

typedef __attribute__((ext_vector_type(8))) short bf16x8;
typedef __attribute__((ext_vector_type(4))) float f32x4;

__device__ __forceinline__ ushort f2bf(float x) {
    union { float f; unsigned u; } v; v.f = x;
    unsigned r = (v.u + 0x7FFFu + ((v.u >> 16) & 1u)) >> 16;   // RNE
    return (ushort)r;
}

__device__ __forceinline__ void gload_lds16(const void* g, void* l) {
    __builtin_amdgcn_global_load_lds(
        (const __attribute__((address_space(1))) void*)g,
        (__attribute__((address_space(3))) void*)l, 16, 0, 0);
}

// ---------------------------------------------------------------------------
// reciprocal of the diagonals of D_v / D_e
// ---------------------------------------------------------------------------
__global__ void k_recip_diag(const float* __restrict__ Dv,
                             const float* __restrict__ De,
                             float* __restrict__ dv_inv,
                             float* __restrict__ de_inv) {
    int i = blockIdx.x * blockDim.x + threadIdx.x;
    if (i < N_NODES) dv_inv[i] = 1.0f / Dv[(size_t)i * (N_NODES + 1)];
    if (i < N_EDGES) de_inv[i] = 1.0f / De[(size_t)i * (N_EDGES + 1)];
}

// ---------------------------------------------------------------------------
// thetaT[f][n] = bf16( (X@W)[n][f] )   — [128][4096] bf16
// Block = 8 n-rows, 128 threads (thread = f). Transposed 16B store.
// ---------------------------------------------------------------------------
__global__ void k_theta_t(const float* __restrict__ X,
                          const float* __restrict__ W,
                          ushort* __restrict__ thetaT) {
    __shared__ float Xs[8][F];
    const int r0 = blockIdx.x * 8;
    const int t  = threadIdx.x;  // 0..127 = f
    #pragma unroll
    for (int i = 0; i < 8; ++i)
        Xs[i][t] = X[(size_t)(r0 + i) * F + t];
    __syncthreads();
    float acc[8];
    #pragma unroll
    for (int i = 0; i < 8; ++i) acc[i] = 0.0f;
    for (int k = 0; k < F; ++k) {
        const float w = W[k * F + t];
        #pragma unroll
        for (int i = 0; i < 8; ++i) acc[i] += Xs[i][k] * w;
    }
    ushort u[8];
    #pragma unroll
    for (int i = 0; i < 8; ++i) u[i] = f2bf(acc[i]);
    *(uint4*)&thetaT[(size_t)t * N_NODES + r0] = *(uint4*)u;
}

// ---------------------------------------------------------------------------
// cast H fp32 [n][e] -> H_bf [n][e] bf16  AND  HT_bf [e][n] bf16 (LDS transpose)
// 64x64 tile per block, 256 threads.
// ---------------------------------------------------------------------------
__global__ void k_castH(const float* __restrict__ H,
                        ushort* __restrict__ Hbf,
                        ushort* __restrict__ HTbf) {
    __shared__ float Ls[64][65];
    const int e0 = blockIdx.x * 64;
    const int n0 = blockIdx.y * 64;
    const int t  = threadIdx.x;
    #pragma unroll
    for (int i = 0; i < 4; ++i) {
        const int idx = t + 256 * i;        // float4 index in 64x64 tile
        const int r = idx >> 4, c4 = (idx & 15) * 4;
        const float4 v = *(const float4*)&H[(size_t)(n0 + r) * N_EDGES + e0 + c4];
        ushort4 hb;
        hb.x = f2bf(v.x); hb.y = f2bf(v.y); hb.z = f2bf(v.z); hb.w = f2bf(v.w);
        *(ushort4*)&Hbf[(size_t)(n0 + r) * N_EDGES + e0 + c4] = hb;
        Ls[r][c4 + 0] = v.x; Ls[r][c4 + 1] = v.y;
        Ls[r][c4 + 2] = v.z; Ls[r][c4 + 3] = v.w;
    }
    __syncthreads();
    const int erow = t >> 2;                // 0..63
    const int nseg = (t & 3) * 16;
    ushort tmp[16];
    #pragma unroll
    for (int j = 0; j < 16; ++j) tmp[j] = f2bf(Ls[nseg + j][erow]);
    ushort* dst = &HTbf[(size_t)(e0 + erow) * N_NODES + n0 + nseg];
    *(uint4*)dst        = *(uint4*)&tmp[0];
    *(uint4*)(dst + 8)  = *(uint4*)&tmp[8];
}

// ---------------------------------------------------------------------------
// BT-form MFMA GEMM:  Out[m][f] (+)= rs[m] * sum_k A[m][k] * B[f][k]
//   A: [4096][4096] bf16 row-major, B: [128][4096] bf16 row-major
//   Out: [4096][128] fp32 via atomicAdd (K-split partials)
// BM=128, BN=64, BK=64; grid (32, 2, KSPLIT=8); 256 threads = 4 waves.
// ---------------------------------------------------------------------------
__global__ __launch_bounds__(256) void k_gemm_bt(
        const ushort* __restrict__ A,
        const ushort* __restrict__ B,
        const float* __restrict__ row_scale,   // nullptr -> 1.0
        float* __restrict__ Out) {
    __shared__ ushort As[128 * 64];   // 16 KB  [m-local][k-local]
    __shared__ ushort Bs[64 * 64];    //  8 KB  [f-local][k-local]
    const int t     = threadIdx.x;
    const int m0    = blockIdx.x * 128;
    const int f0    = blockIdx.y * 64;
    const int kbase = blockIdx.z * (4096 / 8);
    const int lane  = t & 63;
    const int wave  = t >> 6;
    const int mm    = lane & 15;
    const int quad  = lane >> 4;

    f32x4 acc[2][4];
    #pragma unroll
    for (int s = 0; s < 2; ++s)
        #pragma unroll
        for (int fs = 0; fs < 4; ++fs)
            acc[s][fs] = (f32x4){0.f, 0.f, 0.f, 0.f};

    for (int ch = 0; ch < 8; ++ch) {
        const int gk = kbase + ch * 64;
        // stage A tile: 128 rows x 128 B, wave-lane-contiguous LDS
        #pragma unroll
        for (int i = 0; i < 4; ++i) {
            const int flat = (i * 256 + t) * 16;          // byte offset in As
            const int row = flat >> 7, ro = flat & 127;
            gload_lds16((const char*)A + ((size_t)(m0 + row) * 4096 + gk) * 2 + ro,
                        (char*)As + flat);
        }
        // stage B tile: 64 rows x 128 B
        #pragma unroll
        for (int i = 0; i < 2; ++i) {
            const int flat = (i * 256 + t) * 16;
            const int row = flat >> 7, ro = flat & 127;
            gload_lds16((const char*)B + ((size_t)(f0 + row) * 4096 + gk) * 2 + ro,
                        (char*)Bs + flat);
        }
        __syncthreads();   // drains vmcnt -> LDS valid
        #pragma unroll
        for (int kk = 0; kk < 2; ++kk) {
            const int ko = kk * 32 + quad * 8;            // element offset in row
            const bf16x8 a0 = *(const bf16x8*)&As[(wave * 32 + mm) * 64 + ko];
            const bf16x8 a1 = *(const bf16x8*)&As[(wave * 32 + 16 + mm) * 64 + ko];
            #pragma unroll
            for (int fs = 0; fs < 4; ++fs) {
                const bf16x8 b = *(const bf16x8*)&Bs[(fs * 16 + mm) * 64 + ko];
                acc[0][fs] = __builtin_amdgcn_mfma_f32_16x16x32_bf16(a0, b, acc[0][fs], 0, 0, 0);
                acc[1][fs] = __builtin_amdgcn_mfma_f32_16x16x32_bf16(a1, b, acc[1][fs], 0, 0, 0);
            }
        }
        __syncthreads();   // protect LDS before next stage
    }
    // epilogue: C/D layout col=lane&15, row=quad*4+reg
    #pragma unroll
    for (int s = 0; s < 2; ++s) {
        const int rowb = m0 + wave * 32 + s * 16 + quad * 4;
        float rsa[4] = {1.f, 1.f, 1.f, 1.f};
        if (row_scale) {
            const float4 rs = *(const float4*)&row_scale[rowb];
            rsa[0] = rs.x; rsa[1] = rs.y; rsa[2] = rs.z; rsa[3] = rs.w;
        }
        #pragma unroll
        for (int fs = 0; fs < 4; ++fs) {
            const int col = f0 + fs * 16 + mm;
            #pragma unroll
            for (int r = 0; r < 4; ++r)
                atomicAdd(&Out[(size_t)(rowb + r) * F + col], acc[s][fs][r] * rsa[r]);
        }
    }
}

// ---------------------------------------------------------------------------
// MT_bf[f][e] = bf16( de_inv[e] * M_f32[e][f] )  — 64 e-rows per block
// ---------------------------------------------------------------------------
__global__ void k_scaleM(const float* __restrict__ M,
                         const float* __restrict__ de_inv,
                         ushort* __restrict__ MT) {
    __shared__ float Ls[64][132];
    const int e0 = blockIdx.x * 64;
    const int t  = threadIdx.x;
    #pragma unroll
    for (int i = 0; i < 8; ++i) {
        const int idx = t + 256 * i;        // float4 index in 64x128 tile
        const int r = idx >> 5, c4 = (idx & 31) * 4;
        float4 v = *(const float4*)&M[(size_t)(e0 + r) * F + c4];
        const float s = de_inv[e0 + r];
        Ls[r][c4 + 0] = v.x * s; Ls[r][c4 + 1] = v.y * s;
        Ls[r][c4 + 2] = v.z * s; Ls[r][c4 + 3] = v.w * s;
    }
    __syncthreads();
    const int f  = t >> 1;                  // 0..127
    const int eh = (t & 1) * 32;
    ushort tmp[32];
    #pragma unroll
    for (int j = 0; j < 32; ++j) tmp[j] = f2bf(Ls[eh + j][f]);
    ushort* dst = &MT[(size_t)f * N_EDGES + e0 + eh];
    #pragma unroll
    for (int q = 0; q < 4; ++q)
        *(uint4*)(dst + q * 8) = *(uint4*)&tmp[q * 8];
}

// ===========================================================================
// Fallback fp32 path (round-1 kernels) — used if ws_size is too small
// ===========================================================================
constexpr int ETILE  = 64;
constexpr int NTILE  = 64;
constexpr int KCHUNK = 32;
constexpr int KSPLIT = 8;

__global__ void k_theta(const float* __restrict__ X,
                        const float* __restrict__ W,
                        float* __restrict__ theta) {
    __shared__ float Xs[8][F];
    const int r0 = blockIdx.x * 8;
    const int t  = threadIdx.x;
    #pragma unroll
    for (int i = 0; i < 8; ++i)
        Xs[i][t] = X[(size_t)(r0 + i) * F + t];
    __syncthreads();
    float acc[8];
    #pragma unroll
    for (int i = 0; i < 8; ++i) acc[i] = 0.0f;
    for (int k = 0; k < F; ++k) {
        const float w = W[k * F + t];
        #pragma unroll
        for (int i = 0; i < 8; ++i) acc[i] += Xs[i][k] * w;
    }
    #pragma unroll
    for (int i = 0; i < 8; ++i)
        theta[(size_t)(r0 + i) * F + t] = acc[i];
}

__global__ void k_edge_agg(const float* __restrict__ H,
                           const float* __restrict__ theta,
                           float* __restrict__ M) {
    __shared__ float Hs[KCHUNK][ETILE];
    __shared__ float Ts[KCHUNK][F];
    const int e0 = blockIdx.x * ETILE;
    const int n0 = blockIdx.y * (N_NODES / KSPLIT);
    const int t  = threadIdx.x;
    const int f4 = (t & 31) * 4;
    const int eb = (t >> 5) * 8;
    float4 acc[8];
    #pragma unroll
    for (int i = 0; i < 8; ++i) acc[i] = make_float4(0.f, 0.f, 0.f, 0.f);
    for (int nc = 0; nc < N_NODES / KSPLIT; nc += KCHUNK) {
        #pragma unroll
        for (int i = 0; i < 2; ++i) {
            const int idx = t + 256 * i;
            const int nn = idx >> 4, ee4 = (idx & 15) * 4;
            *(float4*)&Hs[nn][ee4] =
                *(const float4*)&H[(size_t)(n0 + nc + nn) * N_EDGES + e0 + ee4];
        }
        #pragma unroll
        for (int i = 0; i < 4; ++i) {
            const int idx = t + 256 * i;
            const int nn = idx >> 5, ff4 = (idx & 31) * 4;
            *(float4*)&Ts[nn][ff4] =
                *(const float4*)&theta[(size_t)(n0 + nc + nn) * F + ff4];
        }
        __syncthreads();
        #pragma unroll 8
        for (int nn = 0; nn < KCHUNK; ++nn) {
            const float4 th = *(const float4*)&Ts[nn][f4];
            const float4 h0 = *(const float4*)&Hs[nn][eb];
            const float4 h1 = *(const float4*)&Hs[nn][eb + 4];
            const float hv[8] = {h0.x, h0.y, h0.z, h0.w, h1.x, h1.y, h1.z, h1.w};
            #pragma unroll
            for (int i = 0; i < 8; ++i) {
                acc[i].x += hv[i] * th.x; acc[i].y += hv[i] * th.y;
                acc[i].z += hv[i] * th.z; acc[i].w += hv[i] * th.w;
            }
        }
        __syncthreads();
    }
    #pragma unroll
    for (int i = 0; i < 8; ++i) {
        float* p = &M[(size_t)(e0 + eb + i) * F + f4];
        atomicAdd(p + 0, acc[i].x); atomicAdd(p + 1, acc[i].y);
        atomicAdd(p + 2, acc[i].z); atomicAdd(p + 3, acc[i].w);
    }
}

__global__ void k_node_agg(const float* __restrict__ H,
                           const float* __restrict__ M,
                           const float* __restrict__ dv_inv,
                           const float* __restrict__ de_inv,
                           float* __restrict__ out) {
    __shared__ float Ms[KCHUNK][F];
    __shared__ float Hs[KCHUNK][68];
    const int n0 = blockIdx.x * NTILE;
    const int e0 = blockIdx.y * (N_EDGES / KSPLIT);
    const int t  = threadIdx.x;
    const int f4 = (t & 31) * 4;
    const int nb = (t >> 5) * 8;
    float4 acc[8];
    #pragma unroll
    for (int i = 0; i < 8; ++i) acc[i] = make_float4(0.f, 0.f, 0.f, 0.f);
    for (int ec = 0; ec < N_EDGES / KSPLIT; ec += KCHUNK) {
        #pragma unroll
        for (int i = 0; i < 4; ++i) {
            const int idx = t + 256 * i;
            const int ee = idx >> 5, ff4 = (idx & 31) * 4;
            float4 m = *(const float4*)&M[(size_t)(e0 + ec + ee) * F + ff4];
            const float s = de_inv[e0 + ec + ee];
            m.x *= s; m.y *= s; m.z *= s; m.w *= s;
            *(float4*)&Ms[ee][ff4] = m;
        }
        #pragma unroll
        for (int i = 0; i < 2; ++i) {
            const int idx = t + 256 * i;
            const int nn = idx >> 3, ee4 = (idx & 7) * 4;
            const float4 h =
                *(const float4*)&H[(size_t)(n0 + nn) * N_EDGES + e0 + ec + ee4];
            const float s = dv_inv[n0 + nn];
            Hs[ee4 + 0][nn] = h.x * s; Hs[ee4 + 1][nn] = h.y * s;
            Hs[ee4 + 2][nn] = h.z * s; Hs[ee4 + 3][nn] = h.w * s;
        }
        __syncthreads();
        #pragma unroll 8
        for (int e = 0; e < KCHUNK; ++e) {
            const float4 mv = *(const float4*)&Ms[e][f4];
            const float4 h0 = *(const float4*)&Hs[e][nb];
            const float4 h1 = *(const float4*)&Hs[e][nb + 4];
            const float hv[8] = {h0.x, h0.y, h0.z, h0.w, h1.x, h1.y, h1.z, h1.w};
            #pragma unroll
            for (int i = 0; i < 8; ++i) {
                acc[i].x += hv[i] * mv.x; acc[i].y += hv[i] * mv.y;
                acc[i].z += hv[i] * mv.z; acc[i].w += hv[i] * mv.w;
            }
        }
        __syncthreads();
    }
    #pragma unroll
    for (int i = 0; i < 8; ++i) {
        float* p = &out[(size_t)(n0 + nb + i) * F + f4];
        atomicAdd(p + 0, acc[i].x); atomicAdd(p + 1, acc[i].y);
        atomicAdd(p + 2, acc[i].z); atomicAdd(p + 3, acc[i].w);
    }
}

// ---------------------------------------------------------------------------
extern "C" void kernel_launch(void* const* d_in, const int* in_sizes, int n_in,
                              void* d_out, int out_size, void* d_ws, size_t ws_size,
                              hipStream_t stream) {
    const float* X  = (const float*)d_in[0];   // [N,128]
    const float* H  = (const float*)d_in[1];   // [N,E]
    const float* Dv = (const float*)d_in[2];   // [N,N]
    const float* De = (const float*)d_in[3];   // [E,E]
    const float* W  = (const float*)d_in[4];   // [128,128]
    float* out = (float*)d_out;                // [N,128]
    char* ws = (char*)d_ws;

    // fast-path workspace layout
    const size_t O_HBF  = 0;                          // 32 MB  H_bf  [n][e]
    const size_t O_HTBF = 33554432;                   // 32 MB  HT_bf [e][n]
    const size_t O_MF32 = 67108864;                   //  2 MB  M fp32 [e][f]
    const size_t O_MTBF = 69206016;                   //  1 MB  MT_bf [f][e]
    const size_t O_THT  = 70254592;                   //  1 MB  thetaT [f][n]
    const size_t O_DV   = 71303168;                   // 16 KB
    const size_t O_DE   = 71319552;                   // 16 KB
    const size_t WS_FAST = 71335936;

    if (ws_size >= WS_FAST) {
        ushort* Hbf    = (ushort*)(ws + O_HBF);
        ushort* HTbf   = (ushort*)(ws + O_HTBF);
        float*  Mf32   = (float*)(ws + O_MF32);
        ushort* MTbf   = (ushort*)(ws + O_MTBF);
        ushort* thetaT = (ushort*)(ws + O_THT);
        float*  dv_inv = (float*)(ws + O_DV);
        float*  de_inv = (float*)(ws + O_DE);

        hipMemsetAsync(Mf32, 0, (size_t)N_EDGES * F * sizeof(float), stream);
        hipMemsetAsync(out,  0, (size_t)N_NODES * F * sizeof(float), stream);

        k_recip_diag<<<dim3(N_NODES / 256), dim3(256), 0, stream>>>(Dv, De, dv_inv, de_inv);
        k_theta_t<<<dim3(N_NODES / 8), dim3(128), 0, stream>>>(X, W, thetaT);
        k_castH<<<dim3(N_EDGES / 64, N_NODES / 64), dim3(256), 0, stream>>>(H, Hbf, HTbf);
        // GEMM1: M[e][f] = sum_n HT[e][n] * thetaT[f][n]
        k_gemm_bt<<<dim3(32, 2, 8), dim3(256), 0, stream>>>(HTbf, thetaT, nullptr, Mf32);
        k_scaleM<<<dim3(N_EDGES / 64), dim3(256), 0, stream>>>(Mf32, de_inv, MTbf);
        // GEMM2: out[n][f] = dv_inv[n] * sum_e H[n][e] * MT[f][e]
        k_gemm_bt<<<dim3(32, 2, 8), dim3(256), 0, stream>>>(Hbf, MTbf, dv_inv, out);
    } else {
        // fallback fp32 path (requires ~4.03 MB)
        float* theta  = (float*)ws;
        float* M      = (float*)(ws + (size_t)2 * 1024 * 1024);
        float* dv_inv = (float*)(ws + (size_t)4 * 1024 * 1024);
        float* de_inv = dv_inv + N_NODES;

        hipMemsetAsync(M,   0, (size_t)N_EDGES * F * sizeof(float), stream);
        hipMemsetAsync(out, 0, (size_t)N_NODES * F * sizeof(float), stream);

        k_recip_diag<<<dim3(N_NODES / 256), dim3(256), 0, stream>>>(Dv, De, dv_inv, de_inv);
        k_theta<<<dim3(N_NODES / 8), dim3(128), 0, stream>>>(X, W, theta);
        k_edge_agg<<<dim3(N_EDGES / ETILE, KSPLIT), dim3(256), 0, stream>>>(H, theta, M);
        k_node_agg<<<dim3(N_NODES / NTILE, KSPLIT), dim3(256), 0, stream>>>(H, M, dv_inv, de_inv, out);
    }
}

// Round 3
// 251.510 us; speedup vs baseline: 1.6118x; 1.0327x over previous
//
#include <hip/hip_runtime.h>

// Problem constants (match reference)
constexpr int N = 4096;   // nodes
constexpr int E = 4096;   // hyperedges
constexpr int F = 128;

// GEMM tiling: BM=64 (m rows), BN=128 (= full F), BK=64, K-split 16.
constexpr int KSPLIT = 16;
constexpr int KEXT   = 4096 / KSPLIT;   // 256 k per block
constexpr int BK     = 64;
constexpr int NCH    = KEXT / BK;       // 4 chunks

typedef __attribute__((ext_vector_type(8))) short bf16x8;
typedef __attribute__((ext_vector_type(4))) float f32x4;

__device__ __forceinline__ ushort f2bf_rne(float x) {
    union { float f; unsigned u; } v; v.f = x;
    return (ushort)((v.u + 0x7FFFu + ((v.u >> 16) & 1u)) >> 16);
}

__device__ __forceinline__ void gload_lds16(const void* g, void* l) {
    __builtin_amdgcn_global_load_lds(
        (const __attribute__((address_space(1))) void*)g,
        (__attribute__((address_space(3))) void*)l, 16, 0, 0);
}

// ---------------------------------------------------------------------------
// reciprocal of the diagonals of D_v / D_e
// ---------------------------------------------------------------------------
__global__ void k_recip_diag(const float* __restrict__ Dv,
                             const float* __restrict__ De,
                             float* __restrict__ dv_inv,
                             float* __restrict__ de_inv) {
    int i = blockIdx.x * blockDim.x + threadIdx.x;
    if (i < N) dv_inv[i] = 1.0f / Dv[(size_t)i * (N + 1)];
    if (i < E) de_inv[i] = 1.0f / De[(size_t)i * (E + 1)];
}

// ---------------------------------------------------------------------------
// thetaT[f][n] = bf16( (X@W)[n][f] )   — [128][4096] bf16
// ---------------------------------------------------------------------------
__global__ void k_theta_t(const float* __restrict__ X,
                          const float* __restrict__ W,
                          ushort* __restrict__ thetaT) {
    __shared__ float Xs[8][F];
    const int r0 = blockIdx.x * 8;
    const int t  = threadIdx.x;  // 0..127 = f
    #pragma unroll
    for (int i = 0; i < 8; ++i)
        Xs[i][t] = X[(size_t)(r0 + i) * F + t];
    __syncthreads();
    float acc[8];
    #pragma unroll
    for (int i = 0; i < 8; ++i) acc[i] = 0.0f;
    for (int k = 0; k < F; ++k) {
        const float w = W[k * F + t];
        #pragma unroll
        for (int i = 0; i < 8; ++i) acc[i] += Xs[i][k] * w;
    }
    ushort u[8];
    #pragma unroll
    for (int i = 0; i < 8; ++i) u[i] = f2bf_rne(acc[i]);
    *(uint4*)&thetaT[(size_t)t * N + r0] = *(uint4*)u;
}

// ---------------------------------------------------------------------------
// Fused-cast MFMA GEMM over fp32 H:
//   Out[m][f] (+)= row_scale[m] * sum_k bf16(Hbits)[...] * B[f][k]
//   A_KMAJOR=true : A-tile = H[k_glob][m_glob] (GEMM1: m=e, k=n; H natural rows=k)
//   A_KMAJOR=false: A-tile = H[m_glob][k_glob] (GEMM2: m=n, k=e; H natural rows=m)
//   B: [128][4096] bf16 row-major (k-contiguous). Out: [4096][128] fp32 atomic.
// Grid (64, KSPLIT), 256 threads = 4 waves; wave owns 16 m-rows x 128 f.
// ---------------------------------------------------------------------------
template <bool A_KMAJOR>
__global__ __launch_bounds__(256, 4) void k_hgemm(
        const float* __restrict__ Hg,          // [4096][4096] fp32
        const ushort* __restrict__ B,          // [128][4096] bf16
        const float* __restrict__ row_scale,   // [4096]
        float* __restrict__ Out) {
    __shared__ float  As[BK * 64];   // 16 KB: KMAJOR ? [k][m] : [m][k]
    __shared__ ushort Bs[F * BK];    // 16 KB: [f][k]
    const int t    = threadIdx.x;
    const int m0   = blockIdx.x * 64;
    const int kb   = blockIdx.y * KEXT;
    const int lane = t & 63;
    const int wave = t >> 6;
    const int mm   = lane & 15;
    const int quad = lane >> 4;

    f32x4 acc[8];
    #pragma unroll
    for (int fs = 0; fs < 8; ++fs) acc[fs] = (f32x4){0.f, 0.f, 0.f, 0.f};

    for (int ch = 0; ch < NCH; ++ch) {
        const int kg = kb + ch * BK;
        // A tile: 64 rows x 256 B fp32 (row = k for GEMM1, m for GEMM2)
        #pragma unroll
        for (int i = 0; i < 4; ++i) {
            const int flat = (i * 256 + t) * 16;
            const int row = flat >> 8, ro = flat & 255;
            const char* src = A_KMAJOR
                ? (const char*)Hg + ((size_t)(kg + row) * 4096 + m0) * 4 + ro
                : (const char*)Hg + ((size_t)(m0 + row) * 4096 + kg) * 4 + ro;
            gload_lds16(src, (char*)As + flat);
        }
        // B tile: 128 rows x 128 B bf16
        #pragma unroll
        for (int i = 0; i < 4; ++i) {
            const int flat = (i * 256 + t) * 16;
            const int frow = flat >> 7, ro = flat & 127;
            gload_lds16((const char*)B + ((size_t)frow * 4096 + kg) * 2 + ro,
                        (char*)Bs + flat);
        }
        __syncthreads();
        #pragma unroll
        for (int kk = 0; kk < 2; ++kk) {
            const int ko = kk * 32 + quad * 8;
            // Build A fragment: 8 fp32 -> bf16 (H is {0,1}: truncation exact)
            bf16x8 af;
            if (A_KMAJOR) {
                #pragma unroll
                for (int j = 0; j < 8; ++j) {
                    const float v = As[(ko + j) * 64 + wave * 16 + mm];
                    af[j] = (short)(ushort)(__float_as_uint(v) >> 16);
                }
            } else {
                const float4 v0 = *(const float4*)&As[(wave * 16 + mm) * 64 + ko];
                const float4 v1 = *(const float4*)&As[(wave * 16 + mm) * 64 + ko + 4];
                af[0] = (short)(ushort)(__float_as_uint(v0.x) >> 16);
                af[1] = (short)(ushort)(__float_as_uint(v0.y) >> 16);
                af[2] = (short)(ushort)(__float_as_uint(v0.z) >> 16);
                af[3] = (short)(ushort)(__float_as_uint(v0.w) >> 16);
                af[4] = (short)(ushort)(__float_as_uint(v1.x) >> 16);
                af[5] = (short)(ushort)(__float_as_uint(v1.y) >> 16);
                af[6] = (short)(ushort)(__float_as_uint(v1.z) >> 16);
                af[7] = (short)(ushort)(__float_as_uint(v1.w) >> 16);
            }
            #pragma unroll
            for (int fs = 0; fs < 8; ++fs) {
                const bf16x8 b = *(const bf16x8*)&Bs[(fs * 16 + mm) * BK + ko];
                acc[fs] = __builtin_amdgcn_mfma_f32_16x16x32_bf16(af, b, acc[fs], 0, 0, 0);
            }
        }
        __syncthreads();
    }
    // Epilogue: C/D layout col=lane&15, row=quad*4+reg; scale rows, atomic add.
    const int rowb = m0 + wave * 16 + quad * 4;
    const float4 rs = *(const float4*)&row_scale[rowb];
    const float rsa[4] = {rs.x, rs.y, rs.z, rs.w};
    #pragma unroll
    for (int fs = 0; fs < 8; ++fs) {
        const int col = fs * 16 + mm;
        #pragma unroll
        for (int r = 0; r < 4; ++r)
            atomicAdd(&Out[(size_t)(rowb + r) * F + col], acc[fs][r] * rsa[r]);
    }
}

// ---------------------------------------------------------------------------
// MT_bf[f][e] = bf16( M_f32[e][f] )  — pure transpose, 64 e-rows per block
// ---------------------------------------------------------------------------
__global__ void k_transM(const float* __restrict__ M,
                         ushort* __restrict__ MT) {
    __shared__ float Ls[64][132];
    const int e0 = blockIdx.x * 64;
    const int t  = threadIdx.x;
    #pragma unroll
    for (int i = 0; i < 8; ++i) {
        const int idx = t + 256 * i;        // float4 index in 64x128 tile
        const int r = idx >> 5, c4 = (idx & 31) * 4;
        const float4 v = *(const float4*)&M[(size_t)(e0 + r) * F + c4];
        Ls[r][c4 + 0] = v.x; Ls[r][c4 + 1] = v.y;
        Ls[r][c4 + 2] = v.z; Ls[r][c4 + 3] = v.w;
    }
    __syncthreads();
    const int f  = t >> 1;                  // 0..127
    const int eh = (t & 1) * 32;
    ushort tmp[32];
    #pragma unroll
    for (int j = 0; j < 32; ++j) tmp[j] = f2bf_rne(Ls[eh + j][f]);
    ushort* dst = &MT[(size_t)f * E + e0 + eh];
    #pragma unroll
    for (int q = 0; q < 4; ++q)
        *(uint4*)(dst + q * 8) = *(uint4*)&tmp[q * 8];
}

// ---------------------------------------------------------------------------
extern "C" void kernel_launch(void* const* d_in, const int* in_sizes, int n_in,
                              void* d_out, int out_size, void* d_ws, size_t ws_size,
                              hipStream_t stream) {
    const float* X  = (const float*)d_in[0];   // [N,128]
    const float* H  = (const float*)d_in[1];   // [N,E] fp32 (binary)
    const float* Dv = (const float*)d_in[2];   // [N,N]
    const float* De = (const float*)d_in[3];   // [E,E]
    const float* W  = (const float*)d_in[4];   // [128,128]
    float* out = (float*)d_out;                // [N,128]
    char* ws = (char*)d_ws;

    // workspace layout (~4.25 MB)
    float*  Mf32   = (float*)ws;                                   // 2 MB  [e][f]
    ushort* MTbf   = (ushort*)(ws + (size_t)2 * 1024 * 1024);      // 1 MB  [f][e]
    ushort* thetaT = (ushort*)(ws + (size_t)3 * 1024 * 1024);      // 1 MB  [f][n]
    float*  dv_inv = (float*)(ws + (size_t)4 * 1024 * 1024);       // 16 KB
    float*  de_inv = dv_inv + N;                                   // 16 KB

    hipMemsetAsync(Mf32, 0, (size_t)E * F * sizeof(float), stream);
    hipMemsetAsync(out,  0, (size_t)N * F * sizeof(float), stream);

    k_recip_diag<<<dim3(N / 256), dim3(256), 0, stream>>>(Dv, De, dv_inv, de_inv);
    k_theta_t<<<dim3(N / 8), dim3(128), 0, stream>>>(X, W, thetaT);
    // GEMM1: M[e][f] = de_inv[e] * sum_n H[n][e] * thetaT[f][n]
    k_hgemm<true><<<dim3(E / 64, KSPLIT), dim3(256), 0, stream>>>(H, thetaT, de_inv, Mf32);
    k_transM<<<dim3(E / 64), dim3(256), 0, stream>>>(Mf32, MTbf);
    // GEMM2: out[n][f] = dv_inv[n] * sum_e H[n][e] * MT[f][e]
    k_hgemm<false><<<dim3(N / 64, KSPLIT), dim3(256), 0, stream>>>(H, MTbf, dv_inv, out);
}